// Round 4
// baseline (148.443 us; speedup 1.0000x reference)
//
#include <hip/hip_runtime.h>

#define TOTAL_B   131072
#define IN_FEATS  32
#define STATE     128
#define KDIM      160            // STATE + IN_FEATS
#define BROWS     64             // batch rows per tile
#define THREADS   256            // 4 waves; 2 blocks cover one tile's 8 s-slices
#define GRID      (TOTAL_B / BROWS * 2)   // 4096 blocks

typedef __bf16 bf16x8 __attribute__((ext_vector_type(8)));
typedef float  f32x4  __attribute__((ext_vector_type(4)));

__device__ __forceinline__ float fsigmoid(float x) { return 1.0f / (1.0f + __expf(-x)); }
__device__ __forceinline__ float ftanh(float x)    { return 2.0f / (1.0f + __expf(-2.0f * x)) - 1.0f; }

// Barrier-free, LDS-free LLTM cell.
// Each wave owns: batch tile [tile*64, tile*64+64) x state slice [16*sslice, 16*sslice+16).
// B-fragments (X = [old_h | input]) load directly from global: per (sub,ks) instruction a
// wave's 16 l15-lanes x 4 lg-groups touch 16 full 128B lines, fully consumed. Duplicate
// reads across the 8 waves sharing a tile hit L1/L2/L3 (HBM FETCH unchanged).
__global__ __launch_bounds__(THREADS, 4) void lltm_fused(
    const float* __restrict__ xin,       // [B,32]
    const float* __restrict__ old_h,     // [B,128]
    const float* __restrict__ old_cell,  // [B,128]
    const float* __restrict__ Wt,        // [384,160]
    const float* __restrict__ bias,      // [384]
    float* __restrict__ out)             // new_h [B,128] then new_cell [B,128]
{
    const int t    = threadIdx.x;
    const int lane = t & 63;
    const int wv   = t >> 6;             // 0..3
    const int l15  = lane & 15;
    const int lg   = lane >> 4;          // 0..3

    const int  tile   = blockIdx.x >> 1;
    const int  half   = blockIdx.x & 1;  // which 4 s-slices this block covers
    const int  sslice = half * 4 + wv;   // 0..7
    const int  sbase  = 16 * sslice + 4 * lg;
    const long b0     = (long)tile * BROWS;

    // ---- persistent A fragments (weights as bf16) for this wave's s-slice ----
    // A layout (16x16x32): row = lane&15, k = (lane>>4)*8 + i
    bf16x8 afrag[3][5];
    {
        const int g_lo = 16 * sslice + l15;
        #pragma unroll
        for (int gt = 0; gt < 3; ++gt) {
            #pragma unroll
            for (int ks = 0; ks < 5; ++ks) {
                const float* p = Wt + (size_t)(gt * STATE + g_lo) * KDIM + ks * 32 + lg * 8;
                f32x4 lo = *(const f32x4*)p;
                f32x4 hi = *(const f32x4*)(p + 4);
                bf16x8 a;
                #pragma unroll
                for (int i = 0; i < 4; ++i) { a[i] = (__bf16)lo[i]; a[i + 4] = (__bf16)hi[i]; }
                afrag[gt][ks] = a;
            }
        }
    }

    #pragma unroll
    for (int sub = 0; sub < 4; ++sub) {
        const long row = b0 + sub * 16 + l15;          // this lane's batch row (B col)
        const float* ph = old_h + row * (long)STATE + lg * 8;
        const float* px = xin + row * (long)IN_FEATS + lg * 8;

        // old_cell for the epilogue: issue first, longest slack
        f32x4 oc = *(const f32x4*)(old_cell + row * (long)STATE + sbase);

        // B fragments: k_global = ks*32 + lg*8 + i; ks 0..3 from old_h, ks 4 from xin
        bf16x8 bfr[5];
        #pragma unroll
        for (int ks = 0; ks < 5; ++ks) {
            f32x4 lo = (ks < 4) ? *(const f32x4*)(ph + ks * 32) : *(const f32x4*)px;
            f32x4 hi = (ks < 4) ? *(const f32x4*)(ph + ks * 32 + 4) : *(const f32x4*)(px + 4);
            bf16x8 v;
            #pragma unroll
            for (int j = 0; j < 4; ++j) { v[j] = (__bf16)lo[j]; v[j + 4] = (__bf16)hi[j]; }
            bfr[ks] = v;
        }

        f32x4 acc_ig = {0.f, 0.f, 0.f, 0.f};
        f32x4 acc_og = {0.f, 0.f, 0.f, 0.f};
        f32x4 acc_cc = {0.f, 0.f, 0.f, 0.f};
        #pragma unroll
        for (int ks = 0; ks < 5; ++ks) {
            acc_ig = __builtin_amdgcn_mfma_f32_16x16x32_bf16(afrag[0][ks], bfr[ks], acc_ig, 0, 0, 0);
            acc_og = __builtin_amdgcn_mfma_f32_16x16x32_bf16(afrag[1][ks], bfr[ks], acc_og, 0, 0, 0);
            acc_cc = __builtin_amdgcn_mfma_f32_16x16x32_bf16(afrag[2][ks], bfr[ks], acc_cc, 0, 0, 0);
        }

        // bias from L1 each sub (saves 12 persistent VGPRs)
        f32x4 b_ig = *(const f32x4*)(bias + sbase);
        f32x4 b_og = *(const f32x4*)(bias + STATE + sbase);
        f32x4 b_cc = *(const f32x4*)(bias + 2 * STATE + sbase);

        // epilogue: lane holds batch row `row`, gate-states sbase..sbase+3
        f32x4 nh, nc;
        #pragma unroll
        for (int j = 0; j < 4; ++j) {
            float ig = fsigmoid(acc_ig[j] + b_ig[j]);
            float og = fsigmoid(acc_og[j] + b_og[j]);
            float cp = acc_cc[j] + b_cc[j];
            float cc = cp > 0.f ? cp : (__expf(cp) - 1.0f);
            float c2 = oc[j] + cc * ig;
            nc[j] = c2;
            nh[j] = ftanh(c2) * og;
        }
        __builtin_nontemporal_store(nh, (f32x4*)(out + row * (long)STATE + sbase));
        __builtin_nontemporal_store(nc, (f32x4*)(out + (long)TOTAL_B * STATE + row * (long)STATE + sbase));
    }
}

extern "C" void kernel_launch(void* const* d_in, const int* in_sizes, int n_in,
                              void* d_out, int out_size, void* d_ws, size_t ws_size,
                              hipStream_t stream)
{
    const float* xin      = (const float*)d_in[0];
    const float* old_h    = (const float*)d_in[1];
    const float* old_cell = (const float*)d_in[2];
    const float* Wt       = (const float*)d_in[3];
    const float* bias     = (const float*)d_in[4];
    float* out = (float*)d_out;
    lltm_fused<<<GRID, THREADS, 0, stream>>>(xin, old_h, old_cell, Wt, bias, out);
}